// Round 6
// baseline (1896.105 us; speedup 1.0000x reference)
//
#include <hip/hip_runtime.h>
#include <hip/hip_bf16.h>

#define N_NODES 100000
#define N_EDGES 600000
#define SCAN_BLOCKS ((N_NODES + 255) / 256)   // 391

typedef __bf16 bf16;
typedef __bf16 bf16x2 __attribute__((ext_vector_type(2)));
typedef __bf16 bf16x4 __attribute__((ext_vector_type(4)));
typedef __bf16 bf16x8 __attribute__((ext_vector_type(8)));
typedef float f32x4 __attribute__((ext_vector_type(4)));

// ---------------------------------------------------------------------------
// deg[n] = #edges with from==n (== to-degree by reverse-pair symmetry)
__global__ void deg_hist(const int* __restrict__ from, int* __restrict__ deg, int E) {
    int e = blockIdx.x * blockDim.x + threadIdx.x;
    if (e < E) atomicAdd(&deg[from[e]], 1);
}

// ---- CSR build ----
__global__ __launch_bounds__(256) void block_sums(
    const int* __restrict__ deg, int* __restrict__ bsum)
{
    __shared__ int s[256];
    int i = blockIdx.x * 256 + threadIdx.x;
    s[threadIdx.x] = (i < N_NODES) ? deg[i] : 0;
    __syncthreads();
    for (int st = 128; st > 0; st >>= 1) {
        if (threadIdx.x < st) s[threadIdx.x] += s[threadIdx.x + st];
        __syncthreads();
    }
    if (threadIdx.x == 0) bsum[blockIdx.x] = s[0];
}

__global__ __launch_bounds__(256) void scan_partials(
    const int* __restrict__ bsum, int* __restrict__ bpref, int* __restrict__ off)
{
    __shared__ int s[SCAN_BLOCKS];
    for (int i = threadIdx.x; i < SCAN_BLOCKS; i += 256) s[i] = bsum[i];
    __syncthreads();
    if (threadIdx.x == 0) {
        int run = 0;
        for (int i = 0; i < SCAN_BLOCKS; i++) { int t = s[i]; s[i] = run; run += t; }
        off[N_NODES] = run;   // == N_EDGES
    }
    __syncthreads();
    for (int i = threadIdx.x; i < SCAN_BLOCKS; i += 256) bpref[i] = s[i];
}

__global__ __launch_bounds__(256) void block_scan(
    const int* __restrict__ deg, const int* __restrict__ bpref,
    int* __restrict__ off, int* __restrict__ cursor)
{
    __shared__ int s[256];
    int i = blockIdx.x * 256 + threadIdx.x;
    int v = (i < N_NODES) ? deg[i] : 0;
    s[threadIdx.x] = v;
    __syncthreads();
    for (int st = 1; st < 256; st <<= 1) {
        int x = (threadIdx.x >= st) ? s[threadIdx.x - st] : 0;
        __syncthreads();
        s[threadIdx.x] += x;
        __syncthreads();
    }
    if (i < N_NODES) {
        int o = bpref[blockIdx.x] + s[threadIdx.x] - v;   // exclusive
        off[i] = o;
        cursor[i] = o;
    }
}

// se[p] = e (sorted by from), rank[e] = p
__global__ void scatter_csr(const int* __restrict__ from, int* __restrict__ cursor,
                            int* __restrict__ se, int* __restrict__ rank, int E) {
    int e = blockIdx.x * blockDim.x + threadIdx.x;
    if (e < E) {
        int p = atomicAdd(&cursor[from[e]], 1);
        se[p] = e;
        rank[e] = p;
    }
}

// fromP[i] = from[se[i]]; backP[i] = rank[se[i]^1]
__global__ void make_maps(const int* __restrict__ se, const int* __restrict__ from,
                          const int* __restrict__ rank,
                          int* __restrict__ fromP, int* __restrict__ backP, int E) {
    int i = blockIdx.x * blockDim.x + threadIdx.x;
    if (i < E) {
        int e = se[i];
        fromP[i] = from[e];
        backP[i] = rank[e ^ 1];
    }
}

// ---------------------------------------------------------------------------
// C[M,128] = A[M,64] @ B[64,128] + bias   (node-side GEMM, K=64, fp32 vector)
__global__ __launch_bounds__(256) void node_gemm(
    const float* __restrict__ A, const float* __restrict__ B,
    const float* __restrict__ bias, float* __restrict__ C, int M)
{
    __shared__ float As[16][65];
    __shared__ float Bs[16][128];
    int row0 = blockIdx.x * 64;
    int tid = threadIdx.x;
    int tx = tid & 15, ty = tid >> 4;
    float acc[4][8];
    #pragma unroll
    for (int i = 0; i < 4; i++)
        #pragma unroll
        for (int j = 0; j < 8; j++) acc[i][j] = 0.f;

    for (int kk = 0; kk < 64; kk += 16) {
        int m  = tid >> 2;
        int k4 = (tid & 3) * 4;
        float4 v = make_float4(0.f, 0.f, 0.f, 0.f);
        if (row0 + m < M)
            v = *(const float4*)(A + (size_t)(row0 + m) * 64 + kk + k4);
        As[k4 + 0][m] = v.x; As[k4 + 1][m] = v.y;
        As[k4 + 2][m] = v.z; As[k4 + 3][m] = v.w;
        #pragma unroll
        for (int t = 0; t < 2; t++) {
            int id = tid + t * 256;
            int k = id >> 5, n4 = (id & 31) * 4;
            *(float4*)(&Bs[k][n4]) = *(const float4*)(B + (size_t)(kk + k) * 128 + n4);
        }
        __syncthreads();
        #pragma unroll
        for (int k = 0; k < 16; k++) {
            float a[4], b[8];
            #pragma unroll
            for (int i = 0; i < 4; i++) a[i] = As[k][ty * 4 + i];
            #pragma unroll
            for (int j = 0; j < 8; j++) b[j] = Bs[k][tx + j * 16];
            #pragma unroll
            for (int i = 0; i < 4; i++)
                #pragma unroll
                for (int j = 0; j < 8; j++) acc[i][j] += a[i] * b[j];
        }
        __syncthreads();
    }
    #pragma unroll
    for (int i = 0; i < 4; i++) {
        int r = row0 + ty * 4 + i;
        if (r < M) {
            #pragma unroll
            for (int j = 0; j < 8; j++) {
                int c = tx + j * 16;
                C[(size_t)r * 128 + c] = acc[i][j] + bias[c];
            }
        }
    }
}

// ---------------------------------------------------------------------------
// baseP[i,:] = bf16( nodeW1[fromP[i],:] + ef[se[i],:16]@W2 + (W2_b+W3_b) )
__global__ __launch_bounds__(256) void base_sorted(
    const float* __restrict__ nodeW1, const int* __restrict__ fromP,
    const int* __restrict__ se, const float* __restrict__ ef,
    const float* __restrict__ W2, const float* __restrict__ W2b,
    const float* __restrict__ W3b, bf16* __restrict__ baseP)
{
    int tid = threadIdx.x;
    int c0 = (tid & 31) * 4;
    int sub = tid >> 5;                  // 8 edge slots
    float4 w[16];
    #pragma unroll
    for (int k = 0; k < 16; k++) w[k] = *(const float4*)(W2 + k * 128 + c0);
    float4 bias;
    {
        float4 a = *(const float4*)(W2b + c0);
        float4 b = *(const float4*)(W3b + c0);
        bias = make_float4(a.x + b.x, a.y + b.y, a.z + b.z, a.w + b.w);
    }
    #pragma unroll 1
    for (int it = 0; it < 64; ++it) {
        int i = blockIdx.x * 512 + it * 8 + sub;
        if (i >= N_EDGES) break;
        const float* efr = ef + (size_t)se[i] * 16;
        float4 nv = *(const float4*)(nodeW1 + (size_t)fromP[i] * 128 + c0);
        float4 acc = make_float4(bias.x + nv.x, bias.y + nv.y,
                                 bias.z + nv.z, bias.w + nv.w);
        #pragma unroll
        for (int k = 0; k < 16; k++) {
            float s = efr[k];
            acc.x += s * w[k].x; acc.y += s * w[k].y;
            acc.z += s * w[k].z; acc.w += s * w[k].w;
        }
        bf16x4 o;
        o[0] = (bf16)acc.x; o[1] = (bf16)acc.y; o[2] = (bf16)acc.z; o[3] = (bf16)acc.w;
        *(bf16x4*)(baseP + (size_t)i * 128 + c0) = o;
    }
}

// ---------------------------------------------------------------------------
// W3T[n][k] = bf16(W3[k][n]);  U2T[n][k] = bf16(U2[k][n])   (one-time)
__global__ __launch_bounds__(256) void prep_weights(
    const float* __restrict__ W3, const float* __restrict__ U2,
    bf16* __restrict__ W3T, bf16* __restrict__ U2T)
{
    int i = blockIdx.x * 256 + threadIdx.x;
    if (i < 128 * 128) {
        int k = i >> 7, n = i & 127;
        W3T[n * 128 + k] = (bf16)W3[k * 128 + n];
        U2T[n * 128 + k] = (bf16)U2[k * 128 + n];
    }
}

// ---------------------------------------------------------------------------
// Edge-step GEMM v8 (bf16 MFMA), sorted space — round-0 DATAFLOW (byte-minimal:
// gather gin[backP[i]], linear gout write, separate streaming segsum) with an
// explicit DEPTH-2 SOFTWARE PIPELINE on the A-operand loads:
//   prologue: load tile0's {base, S[fromP], gin[backP]} into registers
//   iter it : issue tile it+1's index+operand loads  -> in flight
//             combine/relu tile it (registers) -> 32 MFMA -> stores
//             rotate next->cur
// The dependent chain (backP[i] -> 256B row gather) is issued one full
// iteration (~400+ cy of MFMA+epilogue) ahead of use, converting the
// latency-bound stall (v6: 2.4 TB/s, 4% MfmaUtil, all pipes idle) into
// overlapped issue. Arrays are indexed only by compile-time kt -> registers.
// B staged once per block into LDS in fragment-major order (conflict-free).
__global__ __launch_bounds__(256) void edge_mfma_v8(
    const bf16* __restrict__ baseP, const bf16* __restrict__ gin,
    const bf16* __restrict__ S, const int* __restrict__ fromP,
    const int* __restrict__ backP, const bf16* __restrict__ BT,
    bf16* __restrict__ gout, int fused)
{
    __shared__ bf16 Bsw[128 * 128];   // 32 KB
    int tid = threadIdx.x;

    // stage B, destination-consecutive (bank-conflict-free LDS writes)
    #pragma unroll
    for (int t = 0; t < 8; t++) {
        int c = tid + t * 256;            // dst chunk id 0..2047
        int cmr = c & 15;
        int cq  = (c >> 4) & 3;
        int ckt = (c >> 6) & 3;
        int cn  = c >> 8;
        int brow = cn * 16 + cmr;
        int bcol = ckt * 32 + cq * 8;
        *(bf16x8*)&Bsw[(size_t)c * 8] =
            *(const bf16x8*)(BT + (size_t)brow * 128 + bcol);
    }
    __syncthreads();

    int wave = tid >> 6, lane = tid & 63;
    int quad = lane >> 4, mr = lane & 15;
    int ibase = blockIdx.x * 256 + wave * 64;
    // grid covers 600064 rows; N_EDGES % 64 == 0 so in-range waves own a full
    // 64-row strip (4 tiles of 16) — no per-tile bounds checks needed.
    if (ibase >= N_EDGES) return;

    // ---- prologue: tile 0 operands -> registers ----
    bf16x8 cbb[4], cgg[4], css[4];
    {
        int i0r = ibase + mr;
        int frc = 0, bkc = 0;
        if (fused) { frc = fromP[i0r]; bkc = backP[i0r]; }
        #pragma unroll
        for (int kt = 0; kt < 4; kt++) {
            int c = kt * 32 + quad * 8;
            cbb[kt] = *(const bf16x8*)(baseP + (size_t)i0r * 128 + c);
            if (fused) {
                cgg[kt] = *(const bf16x8*)(gin + (size_t)bkc * 128 + c);
                css[kt] = *(const bf16x8*)(S   + (size_t)frc * 128 + c);
            }
        }
    }

    #pragma unroll 1
    for (int it = 0; it < 4; ++it) {
        // ---- issue NEXT tile's loads (fire now, consumed next iteration) ----
        bf16x8 nbb[4], ngg[4], nss[4];
        if (it < 3) {
            int i_n = ibase + (it + 1) * 16 + mr;
            int frn = 0, bkn = 0;
            if (fused) { frn = fromP[i_n]; bkn = backP[i_n]; }
            #pragma unroll
            for (int kt = 0; kt < 4; kt++) {
                int c = kt * 32 + quad * 8;
                nbb[kt] = *(const bf16x8*)(baseP + (size_t)i_n * 128 + c);
                if (fused) {
                    ngg[kt] = *(const bf16x8*)(gin + (size_t)bkn * 128 + c);
                    nss[kt] = *(const bf16x8*)(S   + (size_t)frn * 128 + c);
                }
            }
        }

        // ---- combine CURRENT tile from registers ----
        bf16x8 afr[4];
        if (!fused) {
            #pragma unroll
            for (int kt = 0; kt < 4; kt++)
                #pragma unroll
                for (int j = 0; j < 8; j++)
                    afr[kt][j] = (bf16)fmaxf((float)cbb[kt][j], 0.f);
        } else {
            #pragma unroll
            for (int kt = 0; kt < 4; kt++)
                #pragma unroll
                for (int j = 0; j < 8; j++) {
                    float v = (float)cbb[kt][j] + (float)css[kt][j] - (float)cgg[kt][j];
                    afr[kt][j] = (bf16)fmaxf(v, 0.f);
                }
        }

        // ---- MFMA: 8 col-tiles x 4 k-chunks ----
        f32x4 acc[8];
        #pragma unroll
        for (int n = 0; n < 8; n++) acc[n] = (f32x4){0.f, 0.f, 0.f, 0.f};
        #pragma unroll
        for (int kt = 0; kt < 4; kt++) {
            #pragma unroll
            for (int n = 0; n < 8; n++) {
                bf16x8 b = *(const bf16x8*)&Bsw[(size_t)(((n * 4 + kt) * 64) + lane) * 8];
                acc[n] = __builtin_amdgcn_mfma_f32_16x16x32_bf16(afr[kt], b, acc[n], 0, 0, 0);
            }
        }

        // ---- epilogue: C/D layout col=mr, row=quad*4+reg; pack bf16x2 via
        // lane-pair shfl -> 4B stores, 64B segments ----
        int i0 = ibase + it * 16;
        #pragma unroll
        for (int np = 0; np < 4; np++) {
            int n0 = np * 2;
            #pragma unroll
            for (int reg = 0; reg < 4; reg++) {
                float v0 = acc[n0][reg], v1 = acc[n0 + 1][reg];
                float o0 = __shfl_xor(v0, 1);
                float o1 = __shfl_xor(v1, 1);
                bf16x2 pk;
                int colb;
                if ((mr & 1) == 0) {
                    pk[0] = (bf16)v0; pk[1] = (bf16)o0;
                    colb = n0 * 16 + mr;
                } else {
                    pk[0] = (bf16)o1; pk[1] = (bf16)v1;
                    colb = (n0 + 1) * 16 + (mr ^ 1);
                }
                int row = i0 + quad * 4 + reg;
                *(bf16x2*)(gout + (size_t)row * 128 + colb) = pk;
            }
        }

        // ---- rotate pipeline registers ----
        #pragma unroll
        for (int kt = 0; kt < 4; kt++) {
            cbb[kt] = nbb[kt];
            cgg[kt] = ngg[kt];
            css[kt] = nss[kt];
        }
    }
}

// ---------------------------------------------------------------------------
// Streaming segment sum: S[n,:] = bf16( sum_{p=off[n]}^{off[n+1]} g[p,:] )
// Pure contiguous stream read (sorted edge space) — round-0 proven.
__global__ __launch_bounds__(256) void segsum_stream(
    const bf16* __restrict__ g, const int* __restrict__ off, bf16* __restrict__ S)
{
    int n = blockIdx.x * 4 + (threadIdx.x >> 6);
    if (n >= N_NODES) return;
    int lane = threadIdx.x & 63;
    int o0 = off[n], o1 = off[n + 1];
    float a0 = 0.f, a1 = 0.f;
    for (int p = o0; p < o1; ++p) {
        bf16x2 v = *(const bf16x2*)(g + (size_t)p * 128 + lane * 2);
        a0 += (float)v[0];
        a1 += (float)v[1];
    }
    bf16x2 o; o[0] = (bf16)a0; o[1] = (bf16)a1;
    *(bf16x2*)(S + (size_t)n * 128 + lane * 2) = o;
}

// ---------------------------------------------------------------------------
// Readout (fused): in-edge sum of node n gathers gB[backP[p]] over its bucket,
// then out[n,:] = relu(U1x[n,:] + agg + deg*U2b[:]) — no agg round-trip.
// Gathers live in this latency-tolerant thin kernel (25k blocks, no LDS).
__global__ __launch_bounds__(256) void final_gather_out(
    const bf16* __restrict__ gB, const int* __restrict__ off,
    const int* __restrict__ backP, const float* __restrict__ U1x,
    const float* __restrict__ U2b, float* __restrict__ out)
{
    int n = blockIdx.x * 4 + (threadIdx.x >> 6);
    if (n >= N_NODES) return;
    int lane = threadIdx.x & 63;
    int o0 = off[n], o1 = off[n + 1];
    float a0 = 0.f, a1 = 0.f;
    for (int p = o0; p < o1; ++p) {
        int e = backP[p];   // wave-uniform broadcast load
        bf16x2 v = *(const bf16x2*)(gB + (size_t)e * 128 + lane * 2);
        a0 += (float)v[0];
        a1 += (float)v[1];
    }
    float d = (float)(o1 - o0);
    float2 u = *(const float2*)(U1x + (size_t)n * 128 + lane * 2);
    float2 b = *(const float2*)(U2b + lane * 2);
    float r0 = fmaxf(u.x + a0 + d * b.x, 0.f);
    float r1 = fmaxf(u.y + a1 + d * b.y, 0.f);
    *(float2*)(out + (size_t)n * 128 + lane * 2) = make_float2(r0, r1);
}

// ---------------------------------------------------------------------------
extern "C" void kernel_launch(void* const* d_in, const int* in_sizes, int n_in,
                              void* d_out, int out_size, void* d_ws, size_t ws_size,
                              hipStream_t stream) {
    const float* nf  = (const float*)d_in[0];
    const float* ef  = (const float*)d_in[1];
    // d_in[2] edge_hiddens: zeros -> h1 = relu(base); first GEMM uses fused=0
    const int* edges = (const int*)d_in[3];
    const int* from  = edges;
    const float* W1w = (const float*)d_in[4];
    const float* W1b = (const float*)d_in[5];
    const float* W2w = (const float*)d_in[6];
    const float* W2b = (const float*)d_in[7];
    const float* W3w = (const float*)d_in[8];
    const float* W3b = (const float*)d_in[9];
    const float* U1w = (const float*)d_in[10];
    const float* U1b = (const float*)d_in[11];
    const float* U2w = (const float*)d_in[12];
    const float* U2b = (const float*)d_in[13];
    float* out = (float*)d_out;

    const size_t NODE_MAT = (size_t)N_NODES * 128;
    const size_t EDGE_MAT = (size_t)N_EDGES * 128;
    char* w = (char*)d_ws;
    float* nodeW1 = (float*)w; w += NODE_MAT * 4;        // reused as U1x
    bf16*  S      = (bf16*)w;  w += NODE_MAT * 2;
    bf16*  baseP  = (bf16*)w;  w += EDGE_MAT * 2;
    bf16*  g0     = (bf16*)w;  w += EDGE_MAT * 2;
    bf16*  g1     = (bf16*)w;  w += EDGE_MAT * 2;
    bf16*  W3T    = (bf16*)w;  w += 128 * 128 * 2;
    bf16*  U2T    = (bf16*)w;  w += 128 * 128 * 2;
    int*   deg    = (int*)w;   w += (size_t)N_NODES * 4;
    int*   off    = (int*)w;   w += (size_t)(N_NODES + 1) * 4;
    int*   cursor = (int*)w;   w += (size_t)N_NODES * 4;
    int*   bsum   = (int*)w;   w += (size_t)SCAN_BLOCKS * 4;
    int*   bpref  = (int*)w;   w += (size_t)SCAN_BLOCKS * 4;
    int*   se     = (int*)w;   w += (size_t)N_EDGES * 4;
    int*   rank   = (int*)w;   w += (size_t)N_EDGES * 4;
    int*   fromP  = (int*)w;   w += (size_t)N_EDGES * 4;
    int*   backP  = (int*)w;   w += (size_t)N_EDGES * 4;

    // ---- CSR build + sorted-space maps ----
    hipMemsetAsync(deg, 0, (size_t)N_NODES * 4, stream);
    deg_hist<<<(N_EDGES + 255) / 256, 256, 0, stream>>>(from, deg, N_EDGES);
    block_sums<<<SCAN_BLOCKS, 256, 0, stream>>>(deg, bsum);
    scan_partials<<<1, 256, 0, stream>>>(bsum, bpref, off);
    block_scan<<<SCAN_BLOCKS, 256, 0, stream>>>(deg, bpref, off, cursor);
    scatter_csr<<<(N_EDGES + 255) / 256, 256, 0, stream>>>(from, cursor, se, rank, N_EDGES);
    make_maps<<<(N_EDGES + 255) / 256, 256, 0, stream>>>(se, from, rank, fromP, backP, N_EDGES);

    // ---- loop-invariant precompute ----
    prep_weights<<<(128 * 128 + 255) / 256, 256, 0, stream>>>(W3w, U2w, W3T, U2T);
    node_gemm<<<(N_NODES + 63) / 64, 256, 0, stream>>>(nf, W1w, W1b, nodeW1, N_NODES);
    base_sorted<<<(N_EDGES + 511) / 512, 256, 0, stream>>>(
        nodeW1, fromP, se, ef, W2w, W2b, W3b, baseP);

    // ---- message passing (round-0 dataflow, pipelined edge kernel) ----
    const int EGRID = (N_EDGES + 255) / 256;   // 2344
    const int SGRID = (N_NODES + 3) / 4;
    bf16* G[2] = {g0, g1};

    edge_mfma_v8<<<EGRID, 256, 0, stream>>>(
        baseP, G[0], S, fromP, backP, W3T, G[0], 0);
    segsum_stream<<<SGRID, 256, 0, stream>>>(G[0], off, S);
    int cur = 0;
    for (int it = 1; it < 5; ++it) {
        edge_mfma_v8<<<EGRID, 256, 0, stream>>>(
            baseP, G[cur], S, fromP, backP, W3T, G[cur ^ 1], 1);
        cur ^= 1;
        segsum_stream<<<SGRID, 256, 0, stream>>>(G[cur], off, S);
    }
    // readout: h6 built in-flight, B = U2T; then fused to-side gather + out
    edge_mfma_v8<<<EGRID, 256, 0, stream>>>(
        baseP, G[cur], S, fromP, backP, U2T, G[cur ^ 1], 1);
    cur ^= 1;

    node_gemm<<<(N_NODES + 63) / 64, 256, 0, stream>>>(nf, U1w, U1b, nodeW1, N_NODES);
    final_gather_out<<<SGRID, 256, 0, stream>>>(
        G[cur], off, backP, nodeW1, U2b, out);
}

// Round 7
// 1558.644 us; speedup vs baseline: 1.2165x; 1.2165x over previous
//
#include <hip/hip_runtime.h>
#include <hip/hip_bf16.h>

#define N_NODES 100000
#define N_EDGES 600000
#define SCAN_BLOCKS ((N_NODES + 255) / 256)   // 391

typedef __bf16 bf16;
typedef __bf16 bf16x2 __attribute__((ext_vector_type(2)));
typedef __bf16 bf16x4 __attribute__((ext_vector_type(4)));
typedef __bf16 bf16x8 __attribute__((ext_vector_type(8)));
typedef float f32x4 __attribute__((ext_vector_type(4)));

// ---------------------------------------------------------------------------
// deg[n] = #edges with from==n (== to-degree by reverse-pair symmetry)
__global__ void deg_hist(const int* __restrict__ from, int* __restrict__ deg, int E) {
    int e = blockIdx.x * blockDim.x + threadIdx.x;
    if (e < E) atomicAdd(&deg[from[e]], 1);
}

// ---- CSR build ----
__global__ __launch_bounds__(256) void block_sums(
    const int* __restrict__ deg, int* __restrict__ bsum)
{
    __shared__ int s[256];
    int i = blockIdx.x * 256 + threadIdx.x;
    s[threadIdx.x] = (i < N_NODES) ? deg[i] : 0;
    __syncthreads();
    for (int st = 128; st > 0; st >>= 1) {
        if (threadIdx.x < st) s[threadIdx.x] += s[threadIdx.x + st];
        __syncthreads();
    }
    if (threadIdx.x == 0) bsum[blockIdx.x] = s[0];
}

__global__ __launch_bounds__(256) void scan_partials(
    const int* __restrict__ bsum, int* __restrict__ bpref, int* __restrict__ off)
{
    __shared__ int s[SCAN_BLOCKS];
    for (int i = threadIdx.x; i < SCAN_BLOCKS; i += 256) s[i] = bsum[i];
    __syncthreads();
    if (threadIdx.x == 0) {
        int run = 0;
        for (int i = 0; i < SCAN_BLOCKS; i++) { int t = s[i]; s[i] = run; run += t; }
        off[N_NODES] = run;   // == N_EDGES
    }
    __syncthreads();
    for (int i = threadIdx.x; i < SCAN_BLOCKS; i += 256) bpref[i] = s[i];
}

__global__ __launch_bounds__(256) void block_scan(
    const int* __restrict__ deg, const int* __restrict__ bpref,
    int* __restrict__ off, int* __restrict__ cursor)
{
    __shared__ int s[256];
    int i = blockIdx.x * 256 + threadIdx.x;
    int v = (i < N_NODES) ? deg[i] : 0;
    s[threadIdx.x] = v;
    __syncthreads();
    for (int st = 1; st < 256; st <<= 1) {
        int x = (threadIdx.x >= st) ? s[threadIdx.x - st] : 0;
        __syncthreads();
        s[threadIdx.x] += x;
        __syncthreads();
    }
    if (i < N_NODES) {
        int o = bpref[blockIdx.x] + s[threadIdx.x] - v;   // exclusive
        off[i] = o;
        cursor[i] = o;
    }
}

// se[p] = e (sorted by from), rank[e] = p
__global__ void scatter_csr(const int* __restrict__ from, int* __restrict__ cursor,
                            int* __restrict__ se, int* __restrict__ rank, int E) {
    int e = blockIdx.x * blockDim.x + threadIdx.x;
    if (e < E) {
        int p = atomicAdd(&cursor[from[e]], 1);
        se[p] = e;
        rank[e] = p;
    }
}

// fromP[i] = from[se[i]]; backP[i] = rank[se[i]^1]
__global__ void make_maps(const int* __restrict__ se, const int* __restrict__ from,
                          const int* __restrict__ rank,
                          int* __restrict__ fromP, int* __restrict__ backP, int E) {
    int i = blockIdx.x * blockDim.x + threadIdx.x;
    if (i < E) {
        int e = se[i];
        fromP[i] = from[e];
        backP[i] = rank[e ^ 1];
    }
}

// ---------------------------------------------------------------------------
// C[M,128] = A[M,64] @ B[64,128] + bias   (node-side GEMM, K=64, fp32 vector)
__global__ __launch_bounds__(256) void node_gemm(
    const float* __restrict__ A, const float* __restrict__ B,
    const float* __restrict__ bias, float* __restrict__ C, int M)
{
    __shared__ float As[16][65];
    __shared__ float Bs[16][128];
    int row0 = blockIdx.x * 64;
    int tid = threadIdx.x;
    int tx = tid & 15, ty = tid >> 4;
    float acc[4][8];
    #pragma unroll
    for (int i = 0; i < 4; i++)
        #pragma unroll
        for (int j = 0; j < 8; j++) acc[i][j] = 0.f;

    for (int kk = 0; kk < 64; kk += 16) {
        int m  = tid >> 2;
        int k4 = (tid & 3) * 4;
        float4 v = make_float4(0.f, 0.f, 0.f, 0.f);
        if (row0 + m < M)
            v = *(const float4*)(A + (size_t)(row0 + m) * 64 + kk + k4);
        As[k4 + 0][m] = v.x; As[k4 + 1][m] = v.y;
        As[k4 + 2][m] = v.z; As[k4 + 3][m] = v.w;
        #pragma unroll
        for (int t = 0; t < 2; t++) {
            int id = tid + t * 256;
            int k = id >> 5, n4 = (id & 31) * 4;
            *(float4*)(&Bs[k][n4]) = *(const float4*)(B + (size_t)(kk + k) * 128 + n4);
        }
        __syncthreads();
        #pragma unroll
        for (int k = 0; k < 16; k++) {
            float a[4], b[8];
            #pragma unroll
            for (int i = 0; i < 4; i++) a[i] = As[k][ty * 4 + i];
            #pragma unroll
            for (int j = 0; j < 8; j++) b[j] = Bs[k][tx + j * 16];
            #pragma unroll
            for (int i = 0; i < 4; i++)
                #pragma unroll
                for (int j = 0; j < 8; j++) acc[i][j] += a[i] * b[j];
        }
        __syncthreads();
    }
    #pragma unroll
    for (int i = 0; i < 4; i++) {
        int r = row0 + ty * 4 + i;
        if (r < M) {
            #pragma unroll
            for (int j = 0; j < 8; j++) {
                int c = tx + j * 16;
                C[(size_t)r * 128 + c] = acc[i][j] + bias[c];
            }
        }
    }
}

// ---------------------------------------------------------------------------
// baseP[i,:] = bf16( nodeW1[fromP[i],:] + ef[se[i],:16]@W2 + (W2_b+W3_b) )
__global__ __launch_bounds__(256) void base_sorted(
    const float* __restrict__ nodeW1, const int* __restrict__ fromP,
    const int* __restrict__ se, const float* __restrict__ ef,
    const float* __restrict__ W2, const float* __restrict__ W2b,
    const float* __restrict__ W3b, bf16* __restrict__ baseP)
{
    int tid = threadIdx.x;
    int c0 = (tid & 31) * 4;
    int sub = tid >> 5;                  // 8 edge slots
    float4 w[16];
    #pragma unroll
    for (int k = 0; k < 16; k++) w[k] = *(const float4*)(W2 + k * 128 + c0);
    float4 bias;
    {
        float4 a = *(const float4*)(W2b + c0);
        float4 b = *(const float4*)(W3b + c0);
        bias = make_float4(a.x + b.x, a.y + b.y, a.z + b.z, a.w + b.w);
    }
    #pragma unroll 1
    for (int it = 0; it < 64; ++it) {
        int i = blockIdx.x * 512 + it * 8 + sub;
        if (i >= N_EDGES) break;
        const float* efr = ef + (size_t)se[i] * 16;
        float4 nv = *(const float4*)(nodeW1 + (size_t)fromP[i] * 128 + c0);
        float4 acc = make_float4(bias.x + nv.x, bias.y + nv.y,
                                 bias.z + nv.z, bias.w + nv.w);
        #pragma unroll
        for (int k = 0; k < 16; k++) {
            float s = efr[k];
            acc.x += s * w[k].x; acc.y += s * w[k].y;
            acc.z += s * w[k].z; acc.w += s * w[k].w;
        }
        bf16x4 o;
        o[0] = (bf16)acc.x; o[1] = (bf16)acc.y; o[2] = (bf16)acc.z; o[3] = (bf16)acc.w;
        *(bf16x4*)(baseP + (size_t)i * 128 + c0) = o;
    }
}

// ---------------------------------------------------------------------------
// W3T[n][k] = bf16(W3[k][n]);  U2T[n][k] = bf16(U2[k][n])   (one-time)
__global__ __launch_bounds__(256) void prep_weights(
    const float* __restrict__ W3, const float* __restrict__ U2,
    bf16* __restrict__ W3T, bf16* __restrict__ U2T)
{
    int i = blockIdx.x * 256 + threadIdx.x;
    if (i < 128 * 128) {
        int k = i >> 7, n = i & 127;
        W3T[n * 128 + k] = (bf16)W3[k * 128 + n];
        U2T[n * 128 + k] = (bf16)U2[k * 128 + n];
    }
}

// ---------------------------------------------------------------------------
// Edge-step GEMM v9 (bf16 MFMA), sorted space — round-0 per-wave code and
// dataflow (byte-minimal), with TWO occupancy/latency fixes:
//  * 512-thread blocks (8 waves) share one 32 KB B-stage -> occupancy cap
//    rises from 20 waves/CU (LDS-bound at 256 thr) to 24 (VGPR-bound), and
//    B-staging traffic halves.
//  * index pipelining: the 2 index loads (fromP/backP) for tile it+1 are
//    issued before tile it's compute (+2 VGPR), breaking the
//    idx-load -> row-gather serial chain per iteration.
// VGPR stays ~78 (no operand pipelining — round 6 showed that costs more in
// occupancy than it buys in ILP on this latency-bound kernel).
//   A[i,:] = fused ? relu(baseP[i] + S[fromP[i]] - gin[backP[i]]) : relu(baseP[i])
//   gout[i,:] = bf16(A @ B)     (B transposed bf16 [n][k]; gin/gout ping-pong)
// B staged per block into LDS in fragment-major order (conflict-free).
__global__ __launch_bounds__(512) void edge_mfma_v9(
    const bf16* __restrict__ baseP, const bf16* __restrict__ gin,
    const bf16* __restrict__ S, const int* __restrict__ fromP,
    const int* __restrict__ backP, const bf16* __restrict__ BT,
    bf16* __restrict__ gout, int fused)
{
    __shared__ bf16 Bsw[128 * 128];   // 32 KB
    int tid = threadIdx.x;

    // stage B, destination-consecutive (bank-conflict-free LDS writes)
    #pragma unroll
    for (int t = 0; t < 4; t++) {
        int c = tid + t * 512;            // dst chunk id 0..2047
        int cmr = c & 15;
        int cq  = (c >> 4) & 3;
        int ckt = (c >> 6) & 3;
        int cn  = c >> 8;
        int brow = cn * 16 + cmr;
        int bcol = ckt * 32 + cq * 8;
        *(bf16x8*)&Bsw[(size_t)c * 8] =
            *(const bf16x8*)(BT + (size_t)brow * 128 + bcol);
    }
    __syncthreads();

    int wave = tid >> 6, lane = tid & 63;
    int quad = lane >> 4, mr = lane & 15;
    int ibase = blockIdx.x * 512 + wave * 64;
    // N_EDGES % 64 == 0: a wave's 64-row strip is either fully in range or
    // fully out. (Return AFTER the staging+sync above.)
    if (ibase >= N_EDGES) return;

    // index pipeline: current tile's indices in registers
    int frc = 0, bkc = 0;
    if (fused) { frc = fromP[ibase + mr]; bkc = backP[ibase + mr]; }

    #pragma unroll 1
    for (int it = 0; it < 4; ++it) {
        int i0 = ibase + it * 16;
        int i = i0 + mr;

        // ---- issue NEXT tile's index loads (2 x 4B, consumed next iter) ----
        int frn = 0, bkn = 0;
        if (fused && it < 3) { frn = fromP[i + 16]; bkn = backP[i + 16]; }

        // ---- build this lane's 4 A-fragments in registers ----
        bf16x8 afr[4];
        if (!fused) {
            #pragma unroll
            for (int kt = 0; kt < 4; kt++) {
                bf16x8 bb = *(const bf16x8*)(baseP + (size_t)i * 128 + kt * 32 + quad * 8);
                #pragma unroll
                for (int j = 0; j < 8; j++)
                    afr[kt][j] = (bf16)fmaxf((float)bb[j], 0.f);
            }
        } else {
            const bf16* sr = S   + (size_t)frc * 128;
            const bf16* gr = gin + (size_t)bkc * 128;
            #pragma unroll
            for (int kt = 0; kt < 4; kt++) {
                int c = kt * 32 + quad * 8;
                bf16x8 bb = *(const bf16x8*)(baseP + (size_t)i * 128 + c);
                bf16x8 gg = *(const bf16x8*)(gr + c);
                bf16x8 ss = *(const bf16x8*)(sr + c);
                #pragma unroll
                for (int j = 0; j < 8; j++) {
                    float v = (float)bb[j] + (float)ss[j] - (float)gg[j];
                    afr[kt][j] = (bf16)fmaxf(v, 0.f);
                }
            }
        }

        // ---- MFMA: 8 col-tiles x 4 k-chunks ----
        f32x4 acc[8];
        #pragma unroll
        for (int n = 0; n < 8; n++) acc[n] = (f32x4){0.f, 0.f, 0.f, 0.f};
        #pragma unroll
        for (int kt = 0; kt < 4; kt++) {
            #pragma unroll
            for (int n = 0; n < 8; n++) {
                bf16x8 b = *(const bf16x8*)&Bsw[(size_t)(((n * 4 + kt) * 64) + lane) * 8];
                acc[n] = __builtin_amdgcn_mfma_f32_16x16x32_bf16(afr[kt], b, acc[n], 0, 0, 0);
            }
        }

        // ---- epilogue: C/D layout col=mr, row=quad*4+reg; pack bf16x2 via
        // lane-pair shfl -> 4B stores, 64B segments ----
        #pragma unroll
        for (int np = 0; np < 4; np++) {
            int n0 = np * 2;
            #pragma unroll
            for (int reg = 0; reg < 4; reg++) {
                float v0 = acc[n0][reg], v1 = acc[n0 + 1][reg];
                float o0 = __shfl_xor(v0, 1);
                float o1 = __shfl_xor(v1, 1);
                bf16x2 pk;
                int colb;
                if ((mr & 1) == 0) {
                    pk[0] = (bf16)v0; pk[1] = (bf16)o0;
                    colb = n0 * 16 + mr;
                } else {
                    pk[0] = (bf16)o1; pk[1] = (bf16)v1;
                    colb = (n0 + 1) * 16 + (mr ^ 1);
                }
                int row = i0 + quad * 4 + reg;
                *(bf16x2*)(gout + (size_t)row * 128 + colb) = pk;
            }
        }

        // ---- rotate index pipeline ----
        frc = frn; bkc = bkn;
    }
}

// ---------------------------------------------------------------------------
// Streaming segment sum v2: S[n,:] = bf16( sum_{p in bucket n} g[p,:] )
// Wave splits into two 32-lane halves; each half reads a full 256B row per
// iteration (bf16x4/lane) -> 2 rows in flight per wave (2x MLP of v1).
// Final cross-half merge via shfl_xor(.,32).
__global__ __launch_bounds__(256) void segsum_stream2(
    const bf16* __restrict__ g, const int* __restrict__ off, bf16* __restrict__ S)
{
    int n = blockIdx.x * 4 + (threadIdx.x >> 6);
    if (n >= N_NODES) return;
    int lane = threadIdx.x & 63;
    int half = lane >> 5;
    int c4 = (lane & 31) * 4;
    int o0 = off[n], o1 = off[n + 1];
    float a0 = 0.f, a1 = 0.f, a2 = 0.f, a3 = 0.f;
    for (int p = o0 + half; p < o1; p += 2) {
        bf16x4 v = *(const bf16x4*)(g + (size_t)p * 128 + c4);
        a0 += (float)v[0]; a1 += (float)v[1];
        a2 += (float)v[2]; a3 += (float)v[3];
    }
    a0 += __shfl_xor(a0, 32); a1 += __shfl_xor(a1, 32);
    a2 += __shfl_xor(a2, 32); a3 += __shfl_xor(a3, 32);
    if (half == 0) {
        bf16x4 o;
        o[0] = (bf16)a0; o[1] = (bf16)a1; o[2] = (bf16)a2; o[3] = (bf16)a3;
        *(bf16x4*)(S + (size_t)n * 128 + c4) = o;
    }
}

// ---------------------------------------------------------------------------
// Readout (fused): in-edge sum of node n gathers gB[backP[p]] over its bucket,
// then out[n,:] = relu(U1x[n,:] + agg + deg*U2b[:]) — no agg round-trip.
// Same two-half structure as segsum_stream2 (2 gathered rows in flight).
__global__ __launch_bounds__(256) void final_gather_out(
    const bf16* __restrict__ gB, const int* __restrict__ off,
    const int* __restrict__ backP, const float* __restrict__ U1x,
    const float* __restrict__ U2b, float* __restrict__ out)
{
    int n = blockIdx.x * 4 + (threadIdx.x >> 6);
    if (n >= N_NODES) return;
    int lane = threadIdx.x & 63;
    int half = lane >> 5;
    int c4 = (lane & 31) * 4;
    int o0 = off[n], o1 = off[n + 1];
    float a0 = 0.f, a1 = 0.f, a2 = 0.f, a3 = 0.f;
    for (int p = o0 + half; p < o1; p += 2) {
        int e = backP[p];   // half-uniform broadcast load
        bf16x4 v = *(const bf16x4*)(gB + (size_t)e * 128 + c4);
        a0 += (float)v[0]; a1 += (float)v[1];
        a2 += (float)v[2]; a3 += (float)v[3];
    }
    a0 += __shfl_xor(a0, 32); a1 += __shfl_xor(a1, 32);
    a2 += __shfl_xor(a2, 32); a3 += __shfl_xor(a3, 32);
    if (half == 0) {
        float d = (float)(o1 - o0);
        float4 u = *(const float4*)(U1x + (size_t)n * 128 + c4);
        float4 b = *(const float4*)(U2b + c4);
        float4 r;
        r.x = fmaxf(u.x + a0 + d * b.x, 0.f);
        r.y = fmaxf(u.y + a1 + d * b.y, 0.f);
        r.z = fmaxf(u.z + a2 + d * b.z, 0.f);
        r.w = fmaxf(u.w + a3 + d * b.w, 0.f);
        *(float4*)(out + (size_t)n * 128 + c4) = r;
    }
}

// ---------------------------------------------------------------------------
extern "C" void kernel_launch(void* const* d_in, const int* in_sizes, int n_in,
                              void* d_out, int out_size, void* d_ws, size_t ws_size,
                              hipStream_t stream) {
    const float* nf  = (const float*)d_in[0];
    const float* ef  = (const float*)d_in[1];
    // d_in[2] edge_hiddens: zeros -> h1 = relu(base); first GEMM uses fused=0
    const int* edges = (const int*)d_in[3];
    const int* from  = edges;
    const float* W1w = (const float*)d_in[4];
    const float* W1b = (const float*)d_in[5];
    const float* W2w = (const float*)d_in[6];
    const float* W2b = (const float*)d_in[7];
    const float* W3w = (const float*)d_in[8];
    const float* W3b = (const float*)d_in[9];
    const float* U1w = (const float*)d_in[10];
    const float* U1b = (const float*)d_in[11];
    const float* U2w = (const float*)d_in[12];
    const float* U2b = (const float*)d_in[13];
    float* out = (float*)d_out;

    const size_t NODE_MAT = (size_t)N_NODES * 128;
    const size_t EDGE_MAT = (size_t)N_EDGES * 128;
    char* w = (char*)d_ws;
    float* nodeW1 = (float*)w; w += NODE_MAT * 4;        // reused as U1x
    bf16*  S      = (bf16*)w;  w += NODE_MAT * 2;
    bf16*  baseP  = (bf16*)w;  w += EDGE_MAT * 2;
    bf16*  g0     = (bf16*)w;  w += EDGE_MAT * 2;
    bf16*  g1     = (bf16*)w;  w += EDGE_MAT * 2;
    bf16*  W3T    = (bf16*)w;  w += 128 * 128 * 2;
    bf16*  U2T    = (bf16*)w;  w += 128 * 128 * 2;
    int*   deg    = (int*)w;   w += (size_t)N_NODES * 4;
    int*   off    = (int*)w;   w += (size_t)(N_NODES + 1) * 4;
    int*   cursor = (int*)w;   w += (size_t)N_NODES * 4;
    int*   bsum   = (int*)w;   w += (size_t)SCAN_BLOCKS * 4;
    int*   bpref  = (int*)w;   w += (size_t)SCAN_BLOCKS * 4;
    int*   se     = (int*)w;   w += (size_t)N_EDGES * 4;
    int*   rank   = (int*)w;   w += (size_t)N_EDGES * 4;
    int*   fromP  = (int*)w;   w += (size_t)N_EDGES * 4;
    int*   backP  = (int*)w;   w += (size_t)N_EDGES * 4;

    // ---- CSR build + sorted-space maps ----
    hipMemsetAsync(deg, 0, (size_t)N_NODES * 4, stream);
    deg_hist<<<(N_EDGES + 255) / 256, 256, 0, stream>>>(from, deg, N_EDGES);
    block_sums<<<SCAN_BLOCKS, 256, 0, stream>>>(deg, bsum);
    scan_partials<<<1, 256, 0, stream>>>(bsum, bpref, off);
    block_scan<<<SCAN_BLOCKS, 256, 0, stream>>>(deg, bpref, off, cursor);
    scatter_csr<<<(N_EDGES + 255) / 256, 256, 0, stream>>>(from, cursor, se, rank, N_EDGES);
    make_maps<<<(N_EDGES + 255) / 256, 256, 0, stream>>>(se, from, rank, fromP, backP, N_EDGES);

    // ---- loop-invariant precompute ----
    prep_weights<<<(128 * 128 + 255) / 256, 256, 0, stream>>>(W3w, U2w, W3T, U2T);
    node_gemm<<<(N_NODES + 63) / 64, 256, 0, stream>>>(nf, W1w, W1b, nodeW1, N_NODES);
    base_sorted<<<(N_EDGES + 511) / 512, 256, 0, stream>>>(
        nodeW1, fromP, se, ef, W2w, W2b, W3b, baseP);

    // ---- message passing (round-0 dataflow; 8-wave blocks, idx pipeline) ----
    const int EGRID = (N_EDGES + 511) / 512;   // 1172
    const int SGRID = (N_NODES + 3) / 4;
    bf16* G[2] = {g0, g1};

    edge_mfma_v9<<<EGRID, 512, 0, stream>>>(
        baseP, G[0], S, fromP, backP, W3T, G[0], 0);
    segsum_stream2<<<SGRID, 256, 0, stream>>>(G[0], off, S);
    int cur = 0;
    for (int it = 1; it < 5; ++it) {
        edge_mfma_v9<<<EGRID, 512, 0, stream>>>(
            baseP, G[cur], S, fromP, backP, W3T, G[cur ^ 1], 1);
        cur ^= 1;
        segsum_stream2<<<SGRID, 256, 0, stream>>>(G[cur], off, S);
    }
    // readout: h6 built in-flight, B = U2T; then fused to-side gather + out
    edge_mfma_v9<<<EGRID, 512, 0, stream>>>(
        baseP, G[cur], S, fromP, backP, U2T, G[cur ^ 1], 1);
    cur ^= 1;

    node_gemm<<<(N_NODES + 63) / 64, 256, 0, stream>>>(nf, U1w, U1b, nodeW1, N_NODES);
    final_gather_out<<<SGRID, 256, 0, stream>>>(
        G[cur], off, backP, nodeW1, U2b, out);
}